// Round 1
// baseline (223.953 us; speedup 1.0000x reference)
//
#include <hip/hip_runtime.h>

// y[b,s,n,d] = post[b,s,n] * x[b,s,d] + sum_m comb[b,s,m,n] * residual[b,s,m,d]
// B=4, S=4096, M=4, N=4, D=2048, all float32.
// Pure memory-bound streaming: 1 block per (b,s), float4-vectorized over d.

constexpr int Dc = 2048;
constexpr int Mc = 4;
constexpr int Nc = 4;
constexpr int D4 = Dc / 4;          // 512 float4 per row
constexpr int BLOCK = 256;

__global__ __launch_bounds__(BLOCK) void hcpost_kernel(
    const float* __restrict__ x,
    const float* __restrict__ residual,
    const float* __restrict__ post,
    const float* __restrict__ comb,
    float* __restrict__ out)
{
    const int bs = blockIdx.x;                    // flat (b*S + s)
    const float4* x4 = (const float4*)(x + (size_t)bs * Dc);
    const float4* r4 = (const float4*)(residual + (size_t)bs * Mc * Dc);
    const float*  pp = post + (size_t)bs * Nc;
    const float*  cp = comb + (size_t)bs * Mc * Nc;
    float4*       o4 = (float4*)(out + (size_t)bs * Nc * Dc);

    // Wave-uniform (blockIdx-only) addresses -> compiler emits scalar loads.
    float p[Nc];
    float c[Mc][Nc];
#pragma unroll
    for (int n = 0; n < Nc; ++n) p[n] = pp[n];
#pragma unroll
    for (int m = 0; m < Mc; ++m)
#pragma unroll
        for (int n = 0; n < Nc; ++n) c[m][n] = cp[m * Nc + n];

#pragma unroll
    for (int it = 0; it < D4 / BLOCK; ++it) {     // 2 iterations
        const int i = threadIdx.x + it * BLOCK;   // float4 index along d

        float4 xv = x4[i];
        float4 rv[Mc];
#pragma unroll
        for (int m = 0; m < Mc; ++m) rv[m] = r4[m * D4 + i];

#pragma unroll
        for (int n = 0; n < Nc; ++n) {
            float4 y;
            y.x = p[n] * xv.x;
            y.y = p[n] * xv.y;
            y.z = p[n] * xv.z;
            y.w = p[n] * xv.w;
#pragma unroll
            for (int m = 0; m < Mc; ++m) {
                y.x = fmaf(c[m][n], rv[m].x, y.x);
                y.y = fmaf(c[m][n], rv[m].y, y.y);
                y.z = fmaf(c[m][n], rv[m].z, y.z);
                y.w = fmaf(c[m][n], rv[m].w, y.w);
            }
            o4[n * D4 + i] = y;
        }
    }
}

extern "C" void kernel_launch(void* const* d_in, const int* in_sizes, int n_in,
                              void* d_out, int out_size, void* d_ws, size_t ws_size,
                              hipStream_t stream) {
    const float* x        = (const float*)d_in[0];
    const float* residual = (const float*)d_in[1];
    const float* post     = (const float*)d_in[2];
    const float* comb     = (const float*)d_in[3];
    float* out            = (float*)d_out;

    const int BS = in_sizes[0] / Dc;              // B*S = 16384
    hcpost_kernel<<<BS, BLOCK, 0, stream>>>(x, residual, post, comb, out);
}

// Round 2
// 198.659 us; speedup vs baseline: 1.1273x; 1.1273x over previous
//
#include <hip/hip_runtime.h>

// y[b,s,n,d] = post[b,s,n] * x[b,s,d] + sum_m comb[b,s,m,n] * residual[b,s,m,d]
// B=4, S=4096, M=4, N=4, D=2048, all float32.
// Pure memory-bound streaming (zero reuse) -> nontemporal float4 loads/stores.

constexpr int Dc = 2048;
constexpr int Mc = 4;
constexpr int Nc = 4;
constexpr int D4 = Dc / 4;          // 512 float4 per row
constexpr int BLOCK = 256;

typedef float f4 __attribute__((ext_vector_type(4)));

__global__ __launch_bounds__(BLOCK) void hcpost_kernel(
    const float* __restrict__ x,
    const float* __restrict__ residual,
    const float* __restrict__ post,
    const float* __restrict__ comb,
    float* __restrict__ out)
{
    const int bs = blockIdx.x;                    // flat (b*S + s)
    const f4* x4 = (const f4*)(x + (size_t)bs * Dc);
    const f4* r4 = (const f4*)(residual + (size_t)bs * Mc * Dc);
    const float* pp = post + (size_t)bs * Nc;
    const float* cp = comb + (size_t)bs * Mc * Nc;
    f4* o4 = (f4*)(out + (size_t)bs * Nc * Dc);

    // Wave-uniform (blockIdx-only) addresses -> scalar loads, broadcast free.
    float p[Nc];
    float c[Mc][Nc];
#pragma unroll
    for (int n = 0; n < Nc; ++n) p[n] = pp[n];
#pragma unroll
    for (int m = 0; m < Mc; ++m)
#pragma unroll
        for (int n = 0; n < Nc; ++n) c[m][n] = cp[m * Nc + n];

#pragma unroll
    for (int it = 0; it < D4 / BLOCK; ++it) {     // 2 iterations
        const int i = threadIdx.x + it * BLOCK;   // float4 index along d

        f4 xv = __builtin_nontemporal_load(x4 + i);
        f4 rv[Mc];
#pragma unroll
        for (int m = 0; m < Mc; ++m)
            rv[m] = __builtin_nontemporal_load(r4 + m * D4 + i);

#pragma unroll
        for (int n = 0; n < Nc; ++n) {
            f4 y;
            y.x = p[n] * xv.x;
            y.y = p[n] * xv.y;
            y.z = p[n] * xv.z;
            y.w = p[n] * xv.w;
#pragma unroll
            for (int m = 0; m < Mc; ++m) {
                y.x = fmaf(c[m][n], rv[m].x, y.x);
                y.y = fmaf(c[m][n], rv[m].y, y.y);
                y.z = fmaf(c[m][n], rv[m].z, y.z);
                y.w = fmaf(c[m][n], rv[m].w, y.w);
            }
            __builtin_nontemporal_store(y, o4 + n * D4 + i);
        }
    }
}

extern "C" void kernel_launch(void* const* d_in, const int* in_sizes, int n_in,
                              void* d_out, int out_size, void* d_ws, size_t ws_size,
                              hipStream_t stream) {
    const float* x        = (const float*)d_in[0];
    const float* residual = (const float*)d_in[1];
    const float* post     = (const float*)d_in[2];
    const float* comb     = (const float*)d_in[3];
    float* out            = (float*)d_out;

    const int BS = in_sizes[0] / Dc;              // B*S = 16384
    hcpost_kernel<<<BS, BLOCK, 0, stream>>>(x, residual, post, comb, out);
}